// Round 20
// baseline (167.247 us; speedup 1.0000x reference)
//
#include <hip/hip_runtime.h>

#define B_    4
#define L_    1024
#define D_    16
#define H_    32
#define TAU_  64
#define EMB_  8
#define AEPH_ 34   // ae_ldsh stride (halves)
#define AJP_  36   // aj_ldsh stride (halves): 72B rows -> ~4-way conflict on column reads
#define TI_   32   // tile 32 i x 64 j -> 2048 blocks

typedef _Float16 h2 __attribute__((ext_vector_type(2)));
typedef _Float16 h4 __attribute__((ext_vector_type(4)));
typedef float    f4 __attribute__((ext_vector_type(4)));

union V16 { f4 f; h2 h[4]; };   // 16B raw <-> 4x h2

#if defined(__has_builtin)
#  if __has_builtin(__builtin_amdgcn_fdot2)
#    define FDOT2(a, b, c) __builtin_amdgcn_fdot2((a), (b), (c), false)
#  endif
#endif
#ifndef FDOT2
#  define FDOT2(a, b, c) fmaf((float)(a)[1], (float)(b)[1], \
                          fmaf((float)(a)[0], (float)(b)[0], (c)))
#endif

// ---------------------------------------------------------------------------
// Single fused kernel (R19 body + in-block precompute; kills dispatch #2).
// R19 analysis: total 21.1 = fixed ~8.7 (2 dispatches) + precompute ~2 +
// body ~10.4. Fusion trade: +~1.5us recompute, -one dispatch node and its
// full drain. Phase 1: waves 0-2 compute the block's 96 ai/aj rows (2 thr/
// row, 16 h each) into fp16 LDS; wave 3 computes ae (1 row const; 65x32
// band). One barrier. Phase 2: R19-verbatim fp16 body (lane=j, broadcast
// b128 ai rows, pk_add/pk_max/dot2, NT dword stores -- the only store shape
// that doesn't explode HBM per R12/R16/R18).
// ---------------------------------------------------------------------------
__global__ __launch_bounds__(256, 8) void fused_kernel(
    const float* __restrict__ x, const float* __restrict__ dtt,
    const float* __restrict__ W1, const float* __restrict__ b1,
    const float* __restrict__ W2, const float* __restrict__ b2p,
    float* __restrict__ out)
{
    __shared__ _Float16 ai_ldsh[TI_ * H_];            // 2 KB, 64B rows
    __shared__ _Float16 aj_ldsh[64 * AJP_];           // 4.5 KB, 72B rows
    __shared__ _Float16 ae_ldsh[(TAU_ + 1) * AEPH_];  // 4.4 KB (band only)
    __shared__ _Float16 aec_lds[H_];                  // const-dt ae row

    const int b    = blockIdx.z;
    const int i0   = blockIdx.y * TI_;
    const int j0   = blockIdx.x * 64;
    const int tid  = threadIdx.x;
    const int lane = tid & 63;
    const int w    = __builtin_amdgcn_readfirstlane(tid >> 6);
    const int j    = j0 + lane;

    const bool c0  = (j0 >= i0 + TI_);     // dt==0 over whole tile
    const bool c64 = (i0 >= j0 + 128);     // dt==64 over whole tile
    const bool constpath = c0 || c64;

    // ---- Phase 1a: waves 0-2 -> 96 rows (ai: 0..31 -> i-rows, aj: 32..95). ----
    if (tid < 192) {
        const int r    = tid >> 1;          // 0..95
        const int half = tid & 1;
        const bool isJ = (r >= 32);
        const int grow = isJ ? (j0 + r - 32) : (i0 + r);

        const float4* xr = (const float4*)(x + ((size_t)(b * L_ + grow)) * D_);
        const float4 x0 = xr[0], x1 = xr[1], x2 = xr[2], x3 = xr[3];
        const float xv[D_] = {x0.x, x0.y, x0.z, x0.w, x1.x, x1.y, x1.z, x1.w,
                              x2.x, x2.y, x2.z, x2.w, x3.x, x3.y, x3.z, x3.w};

        const float* Wb = W1 + (isJ ? D_ * H_ : 0) + half * 16;
        float s[16];
#pragma unroll
        for (int k = 0; k < 16; ++k) s[k] = 0.f;
#pragma unroll
        for (int d = 0; d < D_; ++d) {
            const float xd = xv[d];
            const float4* wr = (const float4*)(Wb + d * H_);
            const float4 w0 = wr[0], w1 = wr[1], w2v = wr[2], w3 = wr[3];
            s[0]  = fmaf(xd, w0.x, s[0]);  s[1]  = fmaf(xd, w0.y, s[1]);
            s[2]  = fmaf(xd, w0.z, s[2]);  s[3]  = fmaf(xd, w0.w, s[3]);
            s[4]  = fmaf(xd, w1.x, s[4]);  s[5]  = fmaf(xd, w1.y, s[5]);
            s[6]  = fmaf(xd, w1.z, s[6]);  s[7]  = fmaf(xd, w1.w, s[7]);
            s[8]  = fmaf(xd, w2v.x, s[8]); s[9]  = fmaf(xd, w2v.y, s[9]);
            s[10] = fmaf(xd, w2v.z, s[10]); s[11] = fmaf(xd, w2v.w, s[11]);
            s[12] = fmaf(xd, w3.x, s[12]); s[13] = fmaf(xd, w3.y, s[13]);
            s[14] = fmaf(xd, w3.z, s[14]); s[15] = fmaf(xd, w3.w, s[15]);
        }
        const h4 o0 = {(_Float16)s[0],  (_Float16)s[1],  (_Float16)s[2],  (_Float16)s[3]};
        const h4 o1 = {(_Float16)s[4],  (_Float16)s[5],  (_Float16)s[6],  (_Float16)s[7]};
        const h4 o2 = {(_Float16)s[8],  (_Float16)s[9],  (_Float16)s[10], (_Float16)s[11]};
        const h4 o3 = {(_Float16)s[12], (_Float16)s[13], (_Float16)s[14], (_Float16)s[15]};
        if (!isJ) {
            h4* dst = (h4*)&ai_ldsh[r * H_ + half * 16];          // 8B aligned
            dst[0] = o0; dst[1] = o1; dst[2] = o2; dst[3] = o3;
        } else {
            h4* dst = (h4*)&aj_ldsh[(r - 32) * AJP_ + half * 16]; // 8B aligned
            dst[0] = o0; dst[1] = o1; dst[2] = o2; dst[3] = o3;
        }
    } else {
        // ---- Phase 1b: wave 3 -> ae. ----
        const int t = tid - 192;
        if (constpath) {
            if (t < H_) {
                const int dtc = c0 ? 0 : TAU_;
                float s = b1[t];
#pragma unroll
                for (int e = 0; e < EMB_; ++e)
                    s = fmaf(dtt[dtc * EMB_ + e], W1[(2 * D_ + e) * H_ + t], s);
                aec_lds[t] = (_Float16)s;
            }
        } else {
            for (int idx = t; idx < (TAU_ + 1) * H_; idx += 64) {
                const int tt = idx >> 5, h = idx & 31;
                float s = b1[h];
#pragma unroll
                for (int e = 0; e < EMB_; ++e)
                    s = fmaf(dtt[tt * EMB_ + e], W1[(2 * D_ + e) * H_ + h], s);
                ae_ldsh[tt * AEPH_ + h] = (_Float16)s;
            }
        }
    }

    // W2 -> registers (uniform s_loads + cvt; no LDS needed).
    h2 w2r[16];
    {
        const float4* w4 = (const float4*)W2;
#pragma unroll
        for (int q = 0; q < 8; ++q) {
            const float4 v = w4[q];
            w2r[2 * q + 0] = (h2){(_Float16)v.x, (_Float16)v.y};
            w2r[2 * q + 1] = (h2){(_Float16)v.z, (_Float16)v.w};
        }
    }
    const float b2 = *b2p;

    __syncthreads();

    // ---- Phase 2: per-lane aj column, then R19 body. ----
    h2 r2[16];
#pragma unroll
    for (int q = 0; q < 8; ++q) {
        const h4 c = *(const h4*)&aj_ldsh[lane * AJP_ + q * 4];   // ~4-way, one-time
        r2[2 * q + 0] = (h2){c[0], c[1]};
        r2[2 * q + 1] = (h2){c[2], c[3]};
    }
    if (constpath) {
        const h2* aec = (const h2*)aec_lds;   // broadcast reads
#pragma unroll
        for (int q = 0; q < 16; ++q) r2[q] += aec[q];
    }

    const _Float16* aiW = &ai_ldsh[(w * 8) * H_];   // wave's 8 rows
    float* outb = out + ((size_t)b) * L_ * L_ + ((size_t)(i0 + w * 8)) * L_ + j;
    const h2 zh = {(_Float16)0.f, (_Float16)0.f};

    if (constpath) {
        const float pc = b2 - 0.2f * (c0 ? 0.f : (float)TAU_);
        for (int ii = 0; ii < 8; ii += 2) {
            const f4* ar0 = (const f4*)&aiW[(ii + 0) * H_];  // 4 x ds_read_b128
            const f4* ar1 = (const f4*)&aiW[(ii + 1) * H_];
            float a0a = 0.f, a0b = 0.f, a1a = 0.f, a1b = 0.f;
#pragma unroll
            for (int q = 0; q < 4; ++q) {
                V16 u0; u0.f = ar0[q];
                V16 u1; u1.f = ar1[q];
#pragma unroll
                for (int k = 0; k < 4; ++k) {
                    const int m = q * 4 + k;
                    h2 t0 = u0.h[k] + r2[m];                  // v_pk_add_f16
                    h2 t1 = u1.h[k] + r2[m];
                    t0 = __builtin_elementwise_max(t0, zh);   // v_pk_max_f16
                    t1 = __builtin_elementwise_max(t1, zh);
                    if (k & 1) { a0b = FDOT2(t0, w2r[m], a0b);
                                 a1b = FDOT2(t1, w2r[m], a1b); }
                    else       { a0a = FDOT2(t0, w2r[m], a0a);
                                 a1a = FDOT2(t1, w2r[m], a1a); }
                }
            }
            __builtin_nontemporal_store(a0a + a0b + pc, outb + (size_t)(ii + 0) * L_);
            __builtin_nontemporal_store(a1a + a1b + pc, outb + (size_t)(ii + 1) * L_);
        }
    } else {
        for (int ii = 0; ii < 8; ++ii) {
            const int i   = i0 + w * 8 + ii;
            const int d   = i - j;
            const int dt  = d < 0 ? 0 : (d > TAU_ ? TAU_ : d);
            const h2* eL  = (const h2*)&ae_ldsh[dt * AEPH_];  // 4B aligned
            const f4* ar  = (const f4*)&aiW[ii * H_];
            float aa = 0.f, ab = 0.f;
#pragma unroll
            for (int q = 0; q < 4; ++q) {
                V16 u; u.f = ar[q];
#pragma unroll
                for (int k = 0; k < 4; ++k) {
                    const int m = q * 4 + k;
                    h2 t = u.h[k] + r2[m] + eL[m];
                    t = __builtin_elementwise_max(t, zh);
                    if (k & 1) ab = FDOT2(t, w2r[m], ab);
                    else       aa = FDOT2(t, w2r[m], aa);
                }
            }
            __builtin_nontemporal_store(aa + ab + b2 - 0.2f * (float)dt,
                                        outb + (size_t)ii * L_);
        }
    }
}

extern "C" void kernel_launch(void* const* d_in, const int* in_sizes, int n_in,
                              void* d_out, int out_size, void* d_ws, size_t ws_size,
                              hipStream_t stream) {
    const float* x   = (const float*)d_in[0];
    const float* dtt = (const float*)d_in[1];
    const float* W1  = (const float*)d_in[2];
    const float* b1  = (const float*)d_in[3];
    const float* W2  = (const float*)d_in[4];
    const float* b2  = (const float*)d_in[5];
    float* out = (float*)d_out;

    dim3 grid(L_ / 64, L_ / TI_, B_);
    hipLaunchKernelGGL(fused_kernel, grid, dim3(256), 0, stream,
                       x, dtt, W1, b1, W2, b2, out);
}

// Round 21
// 83.453 us; speedup vs baseline: 2.0041x; 2.0041x over previous
//
#include <hip/hip_runtime.h>

#define B_    4
#define L_    1024
#define D_    16
#define H_    32
#define TAU_  64
#define EMB_  8
#define AEPH_ 34   // ae_ldsh stride (halves)
#define AJP_  36   // aj_ldsh stride (halves): 72B rows -> ~4-way conflict on column reads
#define TI_   32   // tile 32 i x 64 j -> 2048 blocks

typedef _Float16 h2 __attribute__((ext_vector_type(2)));
typedef _Float16 h4 __attribute__((ext_vector_type(4)));
typedef float    f4 __attribute__((ext_vector_type(4)));

union V16 { f4 f; h2 h[4]; };   // 16B raw <-> 4x h2

#if defined(__has_builtin)
#  if __has_builtin(__builtin_amdgcn_fdot2)
#    define FDOT2(a, b, c) __builtin_amdgcn_fdot2((a), (b), (c), false)
#  endif
#endif
#ifndef FDOT2
#  define FDOT2(a, b, c) fmaf((float)(a)[1], (float)(b)[1], \
                          fmaf((float)(a)[0], (float)(b)[0], (c)))
#endif

// ---------------------------------------------------------------------------
// Single fused kernel, take 2. R20's 167us was SCRATCH SPILL, not fusion:
// launch_bounds(256,8) = 64-VGPR cap vs phase-1's ~90 VGPR need ->
// VGPR_Count 32 + WRITE 349MB (20x) + VALUBusy <5%. Fix: (256,4) = 128-VGPR
// cap. Occupancy 16 waves/CU -- a <=3% effect (R9/R13) vs ~5-9us dispatch
// saving. Everything else identical to R20:
// Phase 1: waves 0-2 -> 96 ai/aj rows (2thr/row, 16h) into fp16 LDS; wave 3
// -> ae (1 row const / 65x32 band). One barrier.
// Phase 2: R19-verbatim fp16 body (lane=j, broadcast b128 ai rows,
// pk_add/pk_max/dot2 f32-acc, NT dword stores).
// ---------------------------------------------------------------------------
__global__ __launch_bounds__(256, 4) void fused_kernel(
    const float* __restrict__ x, const float* __restrict__ dtt,
    const float* __restrict__ W1, const float* __restrict__ b1,
    const float* __restrict__ W2, const float* __restrict__ b2p,
    float* __restrict__ out)
{
    __shared__ _Float16 ai_ldsh[TI_ * H_];            // 2 KB, 64B rows
    __shared__ _Float16 aj_ldsh[64 * AJP_];           // 4.5 KB, 72B rows
    __shared__ _Float16 ae_ldsh[(TAU_ + 1) * AEPH_];  // 4.4 KB (band only)
    __shared__ _Float16 aec_lds[H_];                  // const-dt ae row

    const int b    = blockIdx.z;
    const int i0   = blockIdx.y * TI_;
    const int j0   = blockIdx.x * 64;
    const int tid  = threadIdx.x;
    const int lane = tid & 63;
    const int w    = __builtin_amdgcn_readfirstlane(tid >> 6);
    const int j    = j0 + lane;

    const bool c0  = (j0 >= i0 + TI_);     // dt==0 over whole tile
    const bool c64 = (i0 >= j0 + 128);     // dt==64 over whole tile
    const bool constpath = c0 || c64;

    // ---- Phase 1a: waves 0-2 -> 96 rows (r<32: ai i-rows; r>=32: aj j-rows). ----
    if (tid < 192) {
        const int r    = tid >> 1;          // 0..95
        const int half = tid & 1;
        const bool isJ = (r >= 32);
        const int grow = isJ ? (j0 + r - 32) : (i0 + r);

        const float4* xr = (const float4*)(x + ((size_t)(b * L_ + grow)) * D_);
        const float4 x0 = xr[0], x1 = xr[1], x2 = xr[2], x3 = xr[3];
        const float xv[D_] = {x0.x, x0.y, x0.z, x0.w, x1.x, x1.y, x1.z, x1.w,
                              x2.x, x2.y, x2.z, x2.w, x3.x, x3.y, x3.z, x3.w};

        const float* Wb = W1 + (isJ ? D_ * H_ : 0) + half * 16;
        float s[16];
#pragma unroll
        for (int k = 0; k < 16; ++k) s[k] = 0.f;
#pragma unroll
        for (int d = 0; d < D_; ++d) {
            const float xd = xv[d];
            const float4* wr = (const float4*)(Wb + d * H_);
            const float4 w0 = wr[0], w1 = wr[1], w2v = wr[2], w3 = wr[3];
            s[0]  = fmaf(xd, w0.x, s[0]);  s[1]  = fmaf(xd, w0.y, s[1]);
            s[2]  = fmaf(xd, w0.z, s[2]);  s[3]  = fmaf(xd, w0.w, s[3]);
            s[4]  = fmaf(xd, w1.x, s[4]);  s[5]  = fmaf(xd, w1.y, s[5]);
            s[6]  = fmaf(xd, w1.z, s[6]);  s[7]  = fmaf(xd, w1.w, s[7]);
            s[8]  = fmaf(xd, w2v.x, s[8]); s[9]  = fmaf(xd, w2v.y, s[9]);
            s[10] = fmaf(xd, w2v.z, s[10]); s[11] = fmaf(xd, w2v.w, s[11]);
            s[12] = fmaf(xd, w3.x, s[12]); s[13] = fmaf(xd, w3.y, s[13]);
            s[14] = fmaf(xd, w3.z, s[14]); s[15] = fmaf(xd, w3.w, s[15]);
        }
        const h4 o0 = {(_Float16)s[0],  (_Float16)s[1],  (_Float16)s[2],  (_Float16)s[3]};
        const h4 o1 = {(_Float16)s[4],  (_Float16)s[5],  (_Float16)s[6],  (_Float16)s[7]};
        const h4 o2 = {(_Float16)s[8],  (_Float16)s[9],  (_Float16)s[10], (_Float16)s[11]};
        const h4 o3 = {(_Float16)s[12], (_Float16)s[13], (_Float16)s[14], (_Float16)s[15]};
        if (!isJ) {
            h4* dst = (h4*)&ai_ldsh[r * H_ + half * 16];          // 8B aligned
            dst[0] = o0; dst[1] = o1; dst[2] = o2; dst[3] = o3;
        } else {
            h4* dst = (h4*)&aj_ldsh[(r - 32) * AJP_ + half * 16]; // 8B aligned
            dst[0] = o0; dst[1] = o1; dst[2] = o2; dst[3] = o3;
        }
    } else {
        // ---- Phase 1b: wave 3 -> ae. ----
        const int t = tid - 192;
        if (constpath) {
            if (t < H_) {
                const int dtc = c0 ? 0 : TAU_;
                float s = b1[t];
#pragma unroll
                for (int e = 0; e < EMB_; ++e)
                    s = fmaf(dtt[dtc * EMB_ + e], W1[(2 * D_ + e) * H_ + t], s);
                aec_lds[t] = (_Float16)s;
            }
        } else {
            for (int idx = t; idx < (TAU_ + 1) * H_; idx += 64) {
                const int tt = idx >> 5, h = idx & 31;
                float s = b1[h];
#pragma unroll
                for (int e = 0; e < EMB_; ++e)
                    s = fmaf(dtt[tt * EMB_ + e], W1[(2 * D_ + e) * H_ + h], s);
                ae_ldsh[tt * AEPH_ + h] = (_Float16)s;
            }
        }
    }

    // W2 -> registers (uniform s_loads + cvt).
    h2 w2r[16];
    {
        const float4* w4 = (const float4*)W2;
#pragma unroll
        for (int q = 0; q < 8; ++q) {
            const float4 v = w4[q];
            w2r[2 * q + 0] = (h2){(_Float16)v.x, (_Float16)v.y};
            w2r[2 * q + 1] = (h2){(_Float16)v.z, (_Float16)v.w};
        }
    }
    const float b2 = *b2p;

    __syncthreads();

    // ---- Phase 2: per-lane aj column, then R19 body. ----
    h2 r2[16];
#pragma unroll
    for (int q = 0; q < 8; ++q) {
        const h4 c = *(const h4*)&aj_ldsh[lane * AJP_ + q * 4];   // ~4-way, one-time
        r2[2 * q + 0] = (h2){c[0], c[1]};
        r2[2 * q + 1] = (h2){c[2], c[3]};
    }
    if (constpath) {
        const h2* aec = (const h2*)aec_lds;   // broadcast reads
#pragma unroll
        for (int q = 0; q < 16; ++q) r2[q] += aec[q];
    }

    const _Float16* aiW = &ai_ldsh[(w * 8) * H_];   // wave's 8 rows
    float* outb = out + ((size_t)b) * L_ * L_ + ((size_t)(i0 + w * 8)) * L_ + j;
    const h2 zh = {(_Float16)0.f, (_Float16)0.f};

    if (constpath) {
        const float pc = b2 - 0.2f * (c0 ? 0.f : (float)TAU_);
        for (int ii = 0; ii < 8; ii += 2) {
            const f4* ar0 = (const f4*)&aiW[(ii + 0) * H_];  // 4 x ds_read_b128
            const f4* ar1 = (const f4*)&aiW[(ii + 1) * H_];
            float a0a = 0.f, a0b = 0.f, a1a = 0.f, a1b = 0.f;
#pragma unroll
            for (int q = 0; q < 4; ++q) {
                V16 u0; u0.f = ar0[q];
                V16 u1; u1.f = ar1[q];
#pragma unroll
                for (int k = 0; k < 4; ++k) {
                    const int m = q * 4 + k;
                    h2 t0 = u0.h[k] + r2[m];                  // v_pk_add_f16
                    h2 t1 = u1.h[k] + r2[m];
                    t0 = __builtin_elementwise_max(t0, zh);   // v_pk_max_f16
                    t1 = __builtin_elementwise_max(t1, zh);
                    if (k & 1) { a0b = FDOT2(t0, w2r[m], a0b);
                                 a1b = FDOT2(t1, w2r[m], a1b); }
                    else       { a0a = FDOT2(t0, w2r[m], a0a);
                                 a1a = FDOT2(t1, w2r[m], a1a); }
                }
            }
            __builtin_nontemporal_store(a0a + a0b + pc, outb + (size_t)(ii + 0) * L_);
            __builtin_nontemporal_store(a1a + a1b + pc, outb + (size_t)(ii + 1) * L_);
        }
    } else {
        for (int ii = 0; ii < 8; ++ii) {
            const int i   = i0 + w * 8 + ii;
            const int d   = i - j;
            const int dt  = d < 0 ? 0 : (d > TAU_ ? TAU_ : d);
            const h2* eL  = (const h2*)&ae_ldsh[dt * AEPH_];  // 4B aligned
            const f4* ar  = (const f4*)&aiW[ii * H_];
            float aa = 0.f, ab = 0.f;
#pragma unroll
            for (int q = 0; q < 4; ++q) {
                V16 u; u.f = ar[q];
#pragma unroll
                for (int k = 0; k < 4; ++k) {
                    const int m = q * 4 + k;
                    h2 t = u.h[k] + r2[m] + eL[m];
                    t = __builtin_elementwise_max(t, zh);
                    if (k & 1) ab = FDOT2(t, w2r[m], ab);
                    else       aa = FDOT2(t, w2r[m], aa);
                }
            }
            __builtin_nontemporal_store(aa + ab + b2 - 0.2f * (float)dt,
                                        outb + (size_t)ii * L_);
        }
    }
}

extern "C" void kernel_launch(void* const* d_in, const int* in_sizes, int n_in,
                              void* d_out, int out_size, void* d_ws, size_t ws_size,
                              hipStream_t stream) {
    const float* x   = (const float*)d_in[0];
    const float* dtt = (const float*)d_in[1];
    const float* W1  = (const float*)d_in[2];
    const float* b1  = (const float*)d_in[3];
    const float* W2  = (const float*)d_in[4];
    const float* b2  = (const float*)d_in[5];
    float* out = (float*)d_out;

    dim3 grid(L_ / 64, L_ / TI_, B_);
    hipLaunchKernelGGL(fused_kernel, grid, dim3(256), 0, stream,
                       x, dtt, W1, b1, W2, b2, out);
}

// Round 22
// 26.566 us; speedup vs baseline: 6.2956x; 3.1414x over previous
//
#include <hip/hip_runtime.h>

#define B_    4
#define L_    1024
#define D_    16
#define H_    32
#define TAU_  64
#define EMB_  8
#define AEPH_ 34   // ae_ldsh stride (halves)
#define AJP_  36   // aj_ldsh stride (halves): 72B rows
#define TI_   32   // tile 32 i x 64 j -> 2048 blocks

typedef _Float16 h2 __attribute__((ext_vector_type(2)));
typedef _Float16 h4 __attribute__((ext_vector_type(4)));
typedef float    f4 __attribute__((ext_vector_type(4)));

union V16 { f4 f; h2 h[4]; };   // 16B raw <-> 4x h2

#if defined(__has_builtin)
#  if __has_builtin(__builtin_amdgcn_fdot2)
#    define FDOT2(a, b, c) __builtin_amdgcn_fdot2((a), (b), (c), false)
#  endif
#endif
#ifndef FDOT2
#  define FDOT2(a, b, c) fmaf((float)(a)[1], (float)(b)[1], \
                          fmaf((float)(a)[0], (float)(b)[0], (c)))
#endif

// ---------------------------------------------------------------------------
// Single fused kernel, take 3 -- register-lean phase 1.
// R20: (256,8) cap 64 vs ~90 need -> massive spill (VGPR 32, WRITE 349MB).
// R21: (256,4) but hipcc still allocated 64 -> partial spill (WRITE 244MB).
// Fix: phase 1 redesigned to FIT 64 VGPRs: each of 192 threads runs TWO
// sequential half-passes (#pragma unroll 1) computing 8 h each: live set =
// xv[16] + s[8] + 2 float4 W + addr ~= 40 VGPRs. Phase 2 (~44) is disjoint.
// Phase 1: threads 0-191 -> 96 ai/aj rows (2 thr/row, 2x8 h); wave 3 -> ae.
// Phase 2: R19-verbatim fp16 body (lane=j, broadcast b128 ai rows,
// pk_add/pk_max/dot2 f32-acc, NT dword stores).
// ---------------------------------------------------------------------------
__global__ __launch_bounds__(256, 4) void fused_kernel(
    const float* __restrict__ x, const float* __restrict__ dtt,
    const float* __restrict__ W1, const float* __restrict__ b1,
    const float* __restrict__ W2, const float* __restrict__ b2p,
    float* __restrict__ out)
{
    __shared__ _Float16 ai_ldsh[TI_ * H_];            // 2 KB, 64B rows
    __shared__ _Float16 aj_ldsh[64 * AJP_];           // 4.6 KB, 72B rows
    __shared__ _Float16 ae_ldsh[(TAU_ + 1) * AEPH_];  // 4.4 KB (band only)
    __shared__ _Float16 aec_lds[H_];                  // const-dt ae row

    const int b    = blockIdx.z;
    const int i0   = blockIdx.y * TI_;
    const int j0   = blockIdx.x * 64;
    const int tid  = threadIdx.x;
    const int lane = tid & 63;
    const int w    = __builtin_amdgcn_readfirstlane(tid >> 6);
    const int j    = j0 + lane;

    const bool c0  = (j0 >= i0 + TI_);     // dt==0 over whole tile
    const bool c64 = (i0 >= j0 + 128);     // dt==64 over whole tile
    const bool constpath = c0 || c64;

    // ---- Phase 1a: threads 0-191 -> 96 rows, 2 thr/row, 2 passes x 8 h. ----
    if (tid < 192) {
        const int r    = tid >> 1;          // 0..95
        const bool isJ = (r >= 32);
        const int grow = isJ ? (j0 + r - 32) : (i0 + r);

        const float4* xr = (const float4*)(x + ((size_t)(b * L_ + grow)) * D_);
        const float4 x0 = xr[0], x1 = xr[1], x2 = xr[2], x3 = xr[3];
        const float xv[D_] = {x0.x, x0.y, x0.z, x0.w, x1.x, x1.y, x1.z, x1.w,
                              x2.x, x2.y, x2.z, x2.w, x3.x, x3.y, x3.z, x3.w};

        const int hbase = (tid & 1) * 16;
        const float* Wbase = W1 + (isJ ? D_ * H_ : 0) + hbase;
        _Float16* dstrow = isJ ? &aj_ldsh[(r - 32) * AJP_ + hbase]
                               : &ai_ldsh[r * H_ + hbase];

#pragma unroll 1
        for (int half = 0; half < 2; ++half) {   // sequential: caps live regs
            const float* Wb = Wbase + half * 8;
            float s[8] = {0.f, 0.f, 0.f, 0.f, 0.f, 0.f, 0.f, 0.f};
#pragma unroll
            for (int d = 0; d < D_; ++d) {
                const float xd = xv[d];
                const float4* wr = (const float4*)(Wb + d * H_);
                const float4 w0 = wr[0], w1 = wr[1];
                s[0] = fmaf(xd, w0.x, s[0]); s[1] = fmaf(xd, w0.y, s[1]);
                s[2] = fmaf(xd, w0.z, s[2]); s[3] = fmaf(xd, w0.w, s[3]);
                s[4] = fmaf(xd, w1.x, s[4]); s[5] = fmaf(xd, w1.y, s[5]);
                s[6] = fmaf(xd, w1.z, s[6]); s[7] = fmaf(xd, w1.w, s[7]);
            }
            const h4 o0 = {(_Float16)s[0], (_Float16)s[1],
                           (_Float16)s[2], (_Float16)s[3]};
            const h4 o1 = {(_Float16)s[4], (_Float16)s[5],
                           (_Float16)s[6], (_Float16)s[7]};
            h4* dst = (h4*)(dstrow + half * 8);   // 16B-aligned
            dst[0] = o0; dst[1] = o1;
        }
    } else {
        // ---- Phase 1b: wave 3 -> ae. ----
        const int t = tid - 192;
        if (constpath) {
            if (t < H_) {
                const int dtc = c0 ? 0 : TAU_;
                float s = b1[t];
#pragma unroll
                for (int e = 0; e < EMB_; ++e)
                    s = fmaf(dtt[dtc * EMB_ + e], W1[(2 * D_ + e) * H_ + t], s);
                aec_lds[t] = (_Float16)s;
            }
        } else {
#pragma unroll 1
            for (int idx = t; idx < (TAU_ + 1) * H_; idx += 64) {
                const int tt = idx >> 5, h = idx & 31;
                float s = b1[h];
#pragma unroll
                for (int e = 0; e < EMB_; ++e)
                    s = fmaf(dtt[tt * EMB_ + e], W1[(2 * D_ + e) * H_ + h], s);
                ae_ldsh[tt * AEPH_ + h] = (_Float16)s;
            }
        }
    }

    // W2 -> registers (uniform s_loads + cvt).
    h2 w2r[16];
    {
        const float4* w4 = (const float4*)W2;
#pragma unroll
        for (int q = 0; q < 8; ++q) {
            const float4 v = w4[q];
            w2r[2 * q + 0] = (h2){(_Float16)v.x, (_Float16)v.y};
            w2r[2 * q + 1] = (h2){(_Float16)v.z, (_Float16)v.w};
        }
    }
    const float b2 = *b2p;

    __syncthreads();

    // ---- Phase 2: per-lane aj column, then R19 body. ----
    h2 r2[16];
#pragma unroll
    for (int q = 0; q < 8; ++q) {
        const h4 c = *(const h4*)&aj_ldsh[lane * AJP_ + q * 4];   // one-time
        r2[2 * q + 0] = (h2){c[0], c[1]};
        r2[2 * q + 1] = (h2){c[2], c[3]};
    }
    if (constpath) {
        const h2* aec = (const h2*)aec_lds;   // broadcast reads
#pragma unroll
        for (int q = 0; q < 16; ++q) r2[q] += aec[q];
    }

    const _Float16* aiW = &ai_ldsh[(w * 8) * H_];   // wave's 8 rows
    float* outb = out + ((size_t)b) * L_ * L_ + ((size_t)(i0 + w * 8)) * L_ + j;
    const h2 zh = {(_Float16)0.f, (_Float16)0.f};

    if (constpath) {
        const float pc = b2 - 0.2f * (c0 ? 0.f : (float)TAU_);
        for (int ii = 0; ii < 8; ii += 2) {
            const f4* ar0 = (const f4*)&aiW[(ii + 0) * H_];  // 4 x ds_read_b128
            const f4* ar1 = (const f4*)&aiW[(ii + 1) * H_];
            float a0a = 0.f, a0b = 0.f, a1a = 0.f, a1b = 0.f;
#pragma unroll
            for (int q = 0; q < 4; ++q) {
                V16 u0; u0.f = ar0[q];
                V16 u1; u1.f = ar1[q];
#pragma unroll
                for (int k = 0; k < 4; ++k) {
                    const int m = q * 4 + k;
                    h2 t0 = u0.h[k] + r2[m];                  // v_pk_add_f16
                    h2 t1 = u1.h[k] + r2[m];
                    t0 = __builtin_elementwise_max(t0, zh);   // v_pk_max_f16
                    t1 = __builtin_elementwise_max(t1, zh);
                    if (k & 1) { a0b = FDOT2(t0, w2r[m], a0b);
                                 a1b = FDOT2(t1, w2r[m], a1b); }
                    else       { a0a = FDOT2(t0, w2r[m], a0a);
                                 a1a = FDOT2(t1, w2r[m], a1a); }
                }
            }
            __builtin_nontemporal_store(a0a + a0b + pc, outb + (size_t)(ii + 0) * L_);
            __builtin_nontemporal_store(a1a + a1b + pc, outb + (size_t)(ii + 1) * L_);
        }
    } else {
        for (int ii = 0; ii < 8; ++ii) {
            const int i   = i0 + w * 8 + ii;
            const int d   = i - j;
            const int dt  = d < 0 ? 0 : (d > TAU_ ? TAU_ : d);
            const h2* eL  = (const h2*)&ae_ldsh[dt * AEPH_];  // 4B aligned
            const f4* ar  = (const f4*)&aiW[ii * H_];
            float aa = 0.f, ab = 0.f;
#pragma unroll
            for (int q = 0; q < 4; ++q) {
                V16 u; u.f = ar[q];
#pragma unroll
                for (int k = 0; k < 4; ++k) {
                    const int m = q * 4 + k;
                    h2 t = u.h[k] + r2[m] + eL[m];
                    t = __builtin_elementwise_max(t, zh);
                    if (k & 1) ab = FDOT2(t, w2r[m], ab);
                    else       aa = FDOT2(t, w2r[m], aa);
                }
            }
            __builtin_nontemporal_store(aa + ab + b2 - 0.2f * (float)dt,
                                        outb + (size_t)ii * L_);
        }
    }
}

extern "C" void kernel_launch(void* const* d_in, const int* in_sizes, int n_in,
                              void* d_out, int out_size, void* d_ws, size_t ws_size,
                              hipStream_t stream) {
    const float* x   = (const float*)d_in[0];
    const float* dtt = (const float*)d_in[1];
    const float* W1  = (const float*)d_in[2];
    const float* b1  = (const float*)d_in[3];
    const float* W2  = (const float*)d_in[4];
    const float* b2  = (const float*)d_in[5];
    float* out = (float*)d_out;

    dim3 grid(L_ / 64, L_ / TI_, B_);
    hipLaunchKernelGGL(fused_kernel, grid, dim3(256), 0, stream,
                       x, dtt, W1, b1, W2, b2, out);
}

// Round 23
// 20.891 us; speedup vs baseline: 8.0058x; 1.2716x over previous
//
#include <hip/hip_runtime.h>

#define B_    4
#define L_    1024
#define D_    16
#define H_    32
#define TAU_  64
#define EMB_  8
#define AEPH_ 34   // ae_ldsh stride in halves
#define TI_   32   // i-tile height: 2048 blocks = 8 blocks/CU

typedef _Float16 h2 __attribute__((ext_vector_type(2)));
typedef float    f4 __attribute__((ext_vector_type(4)));

union V16 { f4 f; h2 h[4]; };   // 16B raw <-> 4x h2

#if defined(__has_builtin)
#  if __has_builtin(__builtin_amdgcn_fdot2)
#    define FDOT2(a, b, c) __builtin_amdgcn_fdot2((a), (b), (c), false)
#  endif
#endif
#ifndef FDOT2
#  define FDOT2(a, b, c) fmaf((float)(a)[1], (float)(b)[1], \
                          fmaf((float)(a)[0], (float)(b)[0], (c)))
#endif

// ---------------------------------------------------------------------------
// Kernel 1: precompute -> fp16 outputs. (R19 verbatim -- session best 21.15us)
// ---------------------------------------------------------------------------
__global__ __launch_bounds__(256) void precompute_kernel(
    const float* __restrict__ x, const float* __restrict__ dtt,
    const float* __restrict__ W1, const float* __restrict__ b1,
    const float* __restrict__ W2,
    _Float16* __restrict__ aih, _Float16* __restrict__ ajh,
    _Float16* __restrict__ aeh, _Float16* __restrict__ w2h)
{
    const int id = blockIdx.x * 256 + threadIdx.x;
    const int NA = B_ * L_ * H_;
    if (id < NA) {
        const int h   = id & (H_ - 1);
        const int row = id >> 5;                 // b*L + l
        const float4* xr4 = (const float4*)(x + row * D_);
        const float4 v0 = xr4[0], v1 = xr4[1], v2 = xr4[2], v3 = xr4[3];
        const float xv[D_] = {v0.x, v0.y, v0.z, v0.w, v1.x, v1.y, v1.z, v1.w,
                              v2.x, v2.y, v2.z, v2.w, v3.x, v3.y, v3.z, v3.w};
        float s1 = 0.f, s2 = 0.f;
#pragma unroll
        for (int d = 0; d < D_; ++d) {
            s1 = fmaf(xv[d], W1[d * H_ + h], s1);
            s2 = fmaf(xv[d], W1[(D_ + d) * H_ + h], s2);
        }
        aih[id] = (_Float16)s1;
        ajh[id] = (_Float16)s2;
    } else {
        const int k = id - NA;
        if (k < (TAU_ + 1) * H_) {
            const int h = k & (H_ - 1);
            const int t = k >> 5;
            float s = b1[h];
#pragma unroll
            for (int e = 0; e < EMB_; ++e)
                s = fmaf(dtt[t * EMB_ + e], W1[(2 * D_ + e) * H_ + h], s);
            aeh[k] = (_Float16)s;
        } else if (k < (TAU_ + 1) * H_ + H_) {
            const int h = k - (TAU_ + 1) * H_;
            w2h[h] = (_Float16)W2[h];
        }
    }
}

// ---------------------------------------------------------------------------
// Kernel 2: bias kernel, fp16-packed (R19 verbatim).
// Body = LDS row reads (4x ds_read_b128/row) + pk_add_f16/pk_max_f16/
// v_dot2_f32_f16 (f32 accum), lane=j, NT dword stores (the only store shape
// that doesn't amplify HBM traffic -- R12/R16/R18 evidence).
// ---------------------------------------------------------------------------
__global__ __launch_bounds__(256, 8) void bias_kernel(
    const _Float16* __restrict__ aih, const _Float16* __restrict__ ajh,
    const _Float16* __restrict__ aeh, const _Float16* __restrict__ w2h,
    const float* __restrict__ b2p, float* __restrict__ out)
{
    __shared__ _Float16 ai_ldsh[TI_ * H_];            // 2 KB
    __shared__ _Float16 ae_ldsh[(TAU_ + 1) * AEPH_];  // 4.4 KB (band only)

    const int b    = blockIdx.z;
    const int i0   = blockIdx.y * TI_;
    const int j0   = blockIdx.x * 64;
    const int tid  = threadIdx.x;
    const int lane = tid & 63;
    const int w    = __builtin_amdgcn_readfirstlane(tid >> 6);
    const int j    = j0 + lane;

    const bool c0  = (j0 >= i0 + TI_);     // dt==0 over whole tile
    const bool c64 = (i0 >= j0 + 128);     // dt==64 over whole tile
    const bool constpath = c0 || c64;

    const float b2 = *b2p;

    // ---- Stage ai tile: 32 rows x 32 halves = 2 KB = 256 x 8B. ----
    {
        const float2* src = (const float2*)(aih + ((size_t)(b * L_ + i0)) * H_);
        ((float2*)ai_ldsh)[tid] = src[tid];
    }

    // Per-lane column vector r2[16] (h2) = aj row (+ ae row on const path).
    h2 r2[16];
    {
        const f4* ajr = (const f4*)(ajh + ((size_t)(b * L_ + j)) * H_);
#pragma unroll
        for (int q = 0; q < 4; ++q) {
            V16 u; u.f = ajr[q];
            r2[q * 4 + 0] = u.h[0]; r2[q * 4 + 1] = u.h[1];
            r2[q * 4 + 2] = u.h[2]; r2[q * 4 + 3] = u.h[3];
        }
    }

    if (constpath) {
        const h2* aec = (const h2*)(aeh + (c0 ? 0 : TAU_) * H_);   // uniform
#pragma unroll
        for (int q = 0; q < 16; ++q) r2[q] += aec[q];
    } else {
        for (int k = tid; k < (TAU_ + 1) * H_; k += 256)
            ae_ldsh[(k >> 5) * AEPH_ + (k & 31)] = aeh[k];
    }
    __syncthreads();   // covers ai_ldsh (all paths) + ae_ldsh (band)

    // W2 in h2 pairs (uniform -> scalar regs).
    h2 w2r[16];
    {
        const h2* wsrc = (const h2*)w2h;
#pragma unroll
        for (int q = 0; q < 16; ++q) w2r[q] = wsrc[q];
    }

    const _Float16* aiW = &ai_ldsh[(w * 8) * H_];   // wave's 8 rows
    float* outb = out + ((size_t)b) * L_ * L_ + ((size_t)(i0 + w * 8)) * L_ + j;
    const h2 zh = {(_Float16)0.f, (_Float16)0.f};

    if (constpath) {
        const float pc = b2 - 0.2f * (c0 ? 0.f : (float)TAU_);
        for (int ii = 0; ii < 8; ii += 2) {
            const f4* ar0 = (const f4*)&aiW[(ii + 0) * H_];  // 4 x ds_read_b128
            const f4* ar1 = (const f4*)&aiW[(ii + 1) * H_];
            float a0a = 0.f, a0b = 0.f, a1a = 0.f, a1b = 0.f;
#pragma unroll
            for (int q = 0; q < 4; ++q) {
                V16 u0; u0.f = ar0[q];
                V16 u1; u1.f = ar1[q];
#pragma unroll
                for (int k = 0; k < 4; ++k) {
                    const int m = q * 4 + k;
                    h2 t0 = u0.h[k] + r2[m];                  // v_pk_add_f16
                    h2 t1 = u1.h[k] + r2[m];
                    t0 = __builtin_elementwise_max(t0, zh);   // v_pk_max_f16
                    t1 = __builtin_elementwise_max(t1, zh);
                    if (k & 1) { a0b = FDOT2(t0, w2r[m], a0b);
                                 a1b = FDOT2(t1, w2r[m], a1b); }
                    else       { a0a = FDOT2(t0, w2r[m], a0a);
                                 a1a = FDOT2(t1, w2r[m], a1a); }
                }
            }
            __builtin_nontemporal_store(a0a + a0b + pc, outb + (size_t)(ii + 0) * L_);
            __builtin_nontemporal_store(a1a + a1b + pc, outb + (size_t)(ii + 1) * L_);
        }
    } else {
        for (int ii = 0; ii < 8; ++ii) {
            const int i   = i0 + w * 8 + ii;
            const int d   = i - j;
            const int dt  = d < 0 ? 0 : (d > TAU_ ? TAU_ : d);
            const h2* eL  = (const h2*)&ae_ldsh[dt * AEPH_];  // 4B aligned
            const f4* ar  = (const f4*)&aiW[ii * H_];
            float aa = 0.f, ab = 0.f;
#pragma unroll
            for (int q = 0; q < 4; ++q) {
                V16 u; u.f = ar[q];
#pragma unroll
                for (int k = 0; k < 4; ++k) {
                    const int m = q * 4 + k;
                    h2 t = u.h[k] + r2[m] + eL[m];
                    t = __builtin_elementwise_max(t, zh);
                    if (k & 1) ab = FDOT2(t, w2r[m], ab);
                    else       aa = FDOT2(t, w2r[m], aa);
                }
            }
            __builtin_nontemporal_store(aa + ab + b2 - 0.2f * (float)dt,
                                        outb + (size_t)ii * L_);
        }
    }
}

extern "C" void kernel_launch(void* const* d_in, const int* in_sizes, int n_in,
                              void* d_out, int out_size, void* d_ws, size_t ws_size,
                              hipStream_t stream) {
    const float* x   = (const float*)d_in[0];
    const float* dtt = (const float*)d_in[1];
    const float* W1  = (const float*)d_in[2];
    const float* b1  = (const float*)d_in[3];
    const float* W2  = (const float*)d_in[4];
    const float* b2  = (const float*)d_in[5];
    float* out = (float*)d_out;

    _Float16* wsh = (_Float16*)d_ws;
    _Float16* aih = wsh;                               // B*L*H halves
    _Float16* ajh = wsh + B_ * L_ * H_;                // B*L*H halves
    _Float16* aeh = wsh + 2 * B_ * L_ * H_;            // 65*H halves
    _Float16* w2h = aeh + (TAU_ + 1) * H_;             // H halves

    const int total  = B_ * L_ * H_ + (TAU_ + 1) * H_ + H_;
    const int blocks = (total + 255) / 256;
    hipLaunchKernelGGL(precompute_kernel, dim3(blocks), dim3(256), 0, stream,
                       x, dtt, W1, b1, W2, aih, ajh, aeh, w2h);

    dim3 grid(L_ / 64, L_ / TI_, B_);
    hipLaunchKernelGGL(bias_kernel, grid, dim3(256), 0, stream,
                       aih, ajh, aeh, w2h, b2, out);
}